// Round 4
// baseline (91004.803 us; speedup 1.0000x reference)
//
#include <hip/hip_runtime.h>
#include <math.h>

// Problem constants
// B=32, T=512, IDIM=512, ODIM=80, L=256, DUNITS=1024, ATT=128, ACH=10, AK=31, PRE=256, POST=512

__device__ __forceinline__ float sigm(float x){ return 1.0f/(1.0f+__expf(-x)); }

// ---------------- workspace layout (floats) ----------------
// OFF_ENC  : 0         (2097152)  enc_proj (B,T,ATT)
// OFF_AW   : 2097152   (16384)    aw (B,T)
// OFF_E    : 2113536   (16384)    e  (B,T)
// OFF_XC   : 2134016   (24576)    xc (B,768)  [att_c | prenet]
// OFF_Z0   : 2158592   (65536)    z0 ping-pong (2,B,1024)
// OFF_Z1   : 2224128   (65536)    z1 ping-pong
// OFF_FWT  : 2355200   (81920)    feat_w transposed (80,1024)
// OFF_WDT  : 2437120   (131072)   w_dec transposed (128,1024)
// OFF_OUTS : 2568192   (655360)   outs_ws (B,80,L)
// OFF_PN1  : 3223552   (4194304)  postnet buf (B,512,L) [word 0 = grid-barrier counter during loop]
// OFF_PN2  : 7417856   (4194304)  [first 32768 double as dec_part[8][32][128] during loop]
// OFF_BSC  : 11612160  (512)
// OFF_BSH  : 11612672  (512)

// ---------------- grid barrier (arrive + spin, device scope; proven in round 1) ----------------
__device__ __forceinline__ void gbar(unsigned* cnt, unsigned target) {
  __syncthreads();
  if (threadIdx.x == 0) {
    __threadfence();
    __hip_atomic_fetch_add(cnt, 1u, __ATOMIC_RELAXED, __HIP_MEMORY_SCOPE_AGENT);
    while (__hip_atomic_load(cnt, __ATOMIC_RELAXED, __HIP_MEMORY_SCOPE_AGENT) < target)
      __builtin_amdgcn_s_sleep(2);
    __threadfence();
  }
  __syncthreads();
}

// ---------------- init ----------------
__global__ void k_init(float* __restrict__ z0, float* __restrict__ c0,
                       float* __restrict__ z1, float* __restrict__ c1,
                       float* __restrict__ aw, float* __restrict__ fw_t, float* __restrict__ wdec_t,
                       const float* __restrict__ feat_w, const float* __restrict__ w_dec,
                       const int* __restrict__ hlens, const int* __restrict__ ylens,
                       float* __restrict__ d_out, float* __restrict__ dec_part,
                       unsigned* __restrict__ barcnt) {
  int i = blockIdx.x*256 + threadIdx.x;
  if (i < 32768) {
    z0[i]=0.f; c0[i]=0.f; z1[i]=0.f; c1[i]=0.f;
  } else if (i < 49152) {
    int j = i - 32768; int b = j >> 9; int t = j & 511;
    int hl = hlens[b];
    aw[j] = (t < hl) ? 1.0f/(float)hl : 0.f;
  } else if (i < 131072) {
    int j = i - 49152; int od = j >> 10, k = j & 1023;
    fw_t[j] = feat_w[k*80 + od];
  } else if (i < 262144) {
    int j = i - 131072; int a = j >> 10, k = j & 1023;
    wdec_t[j] = w_dec[k*128 + a];
  } else if (i < 262176) {
    int b = i - 262144;
    d_out[663552 + b] = (float)ylens[b];
  } else if (i < 294944) {
    dec_part[i - 262176] = 0.f;     // dec partials for step 0 (z0 = 0)
  } else if (i == 294944) {
    *barcnt = 0u;
  }
}

// ---------------- enc_proj = hs @ w_enc + b_enc ----------------
__global__ void k_encproj(const float* __restrict__ hs, const float* __restrict__ w_enc,
                          const float* __restrict__ b_enc, float* __restrict__ enc_proj) {
  __shared__ float hsl[16*512];
  int b = blockIdx.x, t0 = blockIdx.y*16;
  int tid = threadIdx.x;  // 256
  for (int i = tid; i < 16*512; i += 256)
    hsl[i] = hs[(size_t)(b*512 + t0 + (i>>9))*512 + (i&511)];
  __syncthreads();
  int a = tid & 127, tq = tid >> 7;
  float acc[8];
  #pragma unroll
  for (int u=0;u<8;++u) acc[u]=0.f;
  for (int d=0; d<512; ++d) {
    float w = w_enc[d*128 + a];
    #pragma unroll
    for (int u=0;u<8;++u) acc[u] += hsl[(tq*8+u)*512 + d]*w;
  }
  float be = b_enc[a];
  #pragma unroll
  for (int u=0;u<8;++u)
    enc_proj[(size_t)(b*512 + t0 + tq*8 + u)*128 + a] = acc[u] + be;
}

// ---------------- attention energies for one (b, 64-t chunk) pair ----------------
__device__ __forceinline__ void att_e_chunk(
    int pair, int tid, float* __restrict__ sm,
    const float* __restrict__ aw, const float* __restrict__ loc_k,
    const float* __restrict__ w_loc, const float* __restrict__ gvec,
    const float* __restrict__ enc_proj, const float* __restrict__ dec_part,
    const int* __restrict__ hlens, float* __restrict__ e_out) {
  int b = pair >> 3, t0 = (pair & 7)*64;
  float* awin = sm;        // 94
  float* locl = sm + 96;   // 640
  float* redB = sm + 736;  // 128
  if (tid < 94) {
    int idx = t0 - 15 + tid;
    awin[tid] = (idx >= 0 && idx < 512) ? aw[b*512 + idx] : 0.f;
  }
  __syncthreads();
  for (int i = tid; i < 640; i += 256) {
    int c = i >> 6, tt = i & 63;
    float sacc = 0.f;
    #pragma unroll
    for (int k = 0; k < 31; ++k) sacc += awin[tt + k]*loc_k[c*31 + k];
    locl[i] = sacc;
  }
  __syncthreads();
  const int a = tid & 127, th = tid >> 7, wv = tid >> 6;
  float dec_a = 0.f;
  #pragma unroll
  for (int sl = 0; sl < 8; ++sl) dec_a += dec_part[sl*4096 + b*128 + a];
  const float gv = gvec[a];
  float wl[10];
  #pragma unroll
  for (int c = 0; c < 10; ++c) wl[c] = w_loc[c*128 + a];
  for (int tt = 0; tt < 32; ++tt) {
    const int tl = th*32 + tt;
    float sv = enc_proj[(size_t)(b*512 + t0 + tl)*128 + a] + dec_a;
    #pragma unroll
    for (int c = 0; c < 10; ++c) sv += locl[c*64 + tl]*wl[c];
    float v = tanhf(sv)*gv;
    #pragma unroll
    for (int off = 32; off; off >>= 1) v += __shfl_down(v, off);
    if ((tid & 63) == 0) redB[wv*32 + tt] = v;
  }
  __syncthreads();
  if (tid < 64) {
    const int t = t0 + tid;
    float ee = (tid < 32) ? (redB[tid] + redB[32 + tid])
                          : (redB[64 + (tid - 32)] + redB[96 + (tid - 32)]);
    e_out[b*512 + t] = (t < hlens[b]) ? ee : -1e30f;
  }
}

// ---------------- persistent decoder: weights in registers, 4 grid barriers/step ----------------
// grid 256 x 256. thread = (jq = tid>>4, ks = tid&15). Block gid owns j-rows
// {gate*1024 + gid*4 + uo} for gate 0..3, uo 0..3 (same rows for both LSTMs).
// Thread holds the ks-th 1/16 k-slice of its 1 row (jq) of all 4 gate blocks:
// 240 VGPRs of weights. 1 block/CU (142KB LDS) -> 1 wave/SIMD -> 512-VGPR budget.
__global__ __launch_bounds__(256, 1) void k_loop(
    const float* __restrict__ hs, const int* __restrict__ hlens,
    const float* __restrict__ enc_proj, const float* __restrict__ loc_k,
    const float* __restrict__ w_loc, const float* __restrict__ gvec,
    const float* __restrict__ pre_w1, const float* __restrict__ pre_b1,
    const float* __restrict__ pre_w2, const float* __restrict__ pre_b2,
    const float* __restrict__ l0_wih, const float* __restrict__ l0_whh, const float* __restrict__ l0_b,
    const float* __restrict__ l1_wih, const float* __restrict__ l1_whh, const float* __restrict__ l1_b,
    const float* __restrict__ fw_t, const float* __restrict__ feat_b,
    const float* __restrict__ prob_w, const float* __restrict__ prob_b,
    const float* __restrict__ wdec_t,
    float* __restrict__ aw, float* __restrict__ e_buf, float* __restrict__ xc,
    float* __restrict__ z0buf, float* __restrict__ z1buf,
    float* __restrict__ outs_ws, float* __restrict__ probs_out,
    float* __restrict__ dec_part, unsigned* __restrict__ barcnt) {
  __shared__ float sm[35584];   // 142.3 KB
  const int gid = blockIdx.x;
  const int tid = threadIdx.x;
  const int jq = tid >> 4, ks = tid & 15;
  const int gate = jq >> 2, uo = jq & 3;
  const int jrow = gate*1024 + gid*4 + uo;
  float* gb = sm + 34880;   // 16*33 = 528
  float* hb = sm + 35424;   // 128

  // ---- one-time weight preload into registers ----
  float4 wx0[12], wh0[16], wx1[16], wh1[16];
  {
    const float4* p0 = (const float4*)(l0_wih + (size_t)jrow*768 + ks*48);
    #pragma unroll
    for (int q = 0; q < 12; ++q) wx0[q] = p0[q];
    const float4* p1 = (const float4*)(l0_whh + (size_t)jrow*1024 + ks*64);
    #pragma unroll
    for (int q = 0; q < 16; ++q) wh0[q] = p1[q];
    const float4* p2 = (const float4*)(l1_wih + (size_t)jrow*1024 + ks*64);
    #pragma unroll
    for (int q = 0; q < 16; ++q) wx1[q] = p2[q];
    const float4* p3 = (const float4*)(l1_whh + (size_t)jrow*1024 + ks*64);
    #pragma unroll
    for (int q = 0; q < 16; ++q) wh1[q] = p3[q];
  }
  const float bias0 = l0_b[jrow], bias1 = l1_b[jrow];
  float c0r = 0.f, c1r = 0.f;   // c-state in registers (tid<128: owns (b=tid&31, u=gid*4+tid>>5))
  unsigned nbar = 0;

  for (int s = 0; s < 256; ++s) {
    const int p = s & 1;
    const float* z0r = z0buf + p*32768; float* z0w = z0buf + (1-p)*32768;
    const float* z1r = z1buf + p*32768; float* z1w = z1buf + (1-p)*32768;

    // ======== P1: feat/prob/prenet (blocks 0..31) | att_e (blocks 32..255) ========
    if (gid < 32) {
      const int b = gid;
      float* zs   = sm;         // 1024
      float* prev = sm + 1024;  // 80
      float* h1s  = sm + 1104;  // 256
      for (int i = tid; i < 1024; i += 256) zs[i] = z1r[b*1024 + i];
      __syncthreads();
      if (tid < 80) {
        const float4* wp = (const float4*)(fw_t + tid*1024);
        const float4* zp = (const float4*)zs;
        float acc = feat_b[tid];
        for (int k4 = 0; k4 < 256; ++k4) {
          float4 w = wp[k4]; float4 z = zp[k4];
          acc += w.x*z.x + w.y*z.y + w.z*z.z + w.w*z.w;
        }
        prev[tid] = acc;
        if (s > 0) outs_ws[(b*80 + tid)*256 + (s-1)] = acc;
      } else if (tid == 80) {
        const float4* wp = (const float4*)prob_w;
        const float4* zp = (const float4*)zs;
        float acc = prob_b[0];
        for (int k4 = 0; k4 < 256; ++k4) {
          float4 w = wp[k4]; float4 z = zp[k4];
          acc += w.x*z.x + w.y*z.y + w.z*z.z + w.w*z.w;
        }
        if (s > 0) probs_out[b*256 + (s-1)] = acc;
      }
      __syncthreads();
      {
        float acc = pre_b1[tid];
        for (int k = 0; k < 80; ++k) acc += prev[k]*pre_w1[k*256 + tid];
        h1s[tid] = fmaxf(acc, 0.f);
      }
      __syncthreads();
      {
        float acc = pre_b2[tid];
        for (int k = 0; k < 256; ++k) acc += h1s[k]*pre_w2[k*256 + tid];
        xc[b*768 + 512 + tid] = fmaxf(acc, 0.f);
      }
    } else {
      att_e_chunk(gid - 32, tid, sm, aw, loc_k, w_loc, gvec, enc_proj, dec_part, hlens, e_buf);
      if (gid < 64) {
        __syncthreads();
        att_e_chunk(224 + (gid - 32), tid, sm, aw, loc_k, w_loc, gvec, enc_proj, dec_part, hlens, e_buf);
      }
    }
    gbar(barcnt, 256u*(++nbar));

    // ======== P2: softmax + context; zero dec_part ========
    {
      if (gid < 32 && tid < 128) {
        #pragma unroll
        for (int sl = 0; sl < 8; ++sl) dec_part[sl*4096 + gid*128 + tid] = 0.f;
      }
      const int b = gid >> 3, dc = gid & 7;
      float* aws  = sm;        // 512
      float* red8 = sm + 512;  // 8
      float* cred = sm + 520;  // 256
      const float e0 = e_buf[b*512 + tid];
      const float e1 = e_buf[b*512 + 256 + tid];
      float m = fmaxf(e0, e1);
      #pragma unroll
      for (int off = 32; off; off >>= 1) m = fmaxf(m, __shfl_xor(m, off));
      if ((tid & 63) == 0) red8[tid >> 6] = m;
      __syncthreads();
      m = fmaxf(fmaxf(red8[0], red8[1]), fmaxf(red8[2], red8[3]));
      const float p0 = __expf(e0 - m), p1 = __expf(e1 - m);
      float ssum = p0 + p1;
      #pragma unroll
      for (int off = 32; off; off >>= 1) ssum += __shfl_xor(ssum, off);
      if ((tid & 63) == 0) red8[4 + (tid >> 6)] = ssum;
      __syncthreads();
      const float inv = 1.0f/(red8[4] + red8[5] + red8[6] + red8[7]);
      const float a0 = p0*inv, a1 = p1*inv;
      aws[tid] = a0; aws[tid + 256] = a1;
      if (dc == 0) { aw[b*512 + tid] = a0; aw[b*512 + 256 + tid] = a1; }
      __syncthreads();
      const int d = dc*64 + (tid & 63), w = tid >> 6;
      const float* hp  = hs + (size_t)(b*512 + w*128)*512 + d;
      const float* awp = aws + w*128;
      float acc = 0.f;
      #pragma unroll 8
      for (int t = 0; t < 128; ++t) acc += awp[t]*hp[(size_t)t*512];
      cred[w*64 + (tid & 63)] = acc;
      __syncthreads();
      if (tid < 64)
        xc[b*768 + dc*64 + tid] = cred[tid] + cred[64 + tid] + cred[128 + tid] + cred[192 + tid];
    }
    gbar(barcnt, 256u*(++nbar));

    // ======== P3: lstm0 (register weights) + dec_part atomics ========
    {
      const int S0 = 1920;  // 16 x-slices*52 (=832) + 16 h-slices*68 (=1088)
      #pragma unroll 1
      for (int hf = 0; hf < 2; ++hf) {
        __syncthreads();
        for (int i = tid; i < 3072; i += 256) {          // x: 16r * 16s * 12q
          int q = i % 12, rest = i / 12;
          int sx = rest & 15, r = rest >> 4;
          *(float4*)(sm + r*S0 + sx*52 + q*4) =
              *(const float4*)(xc + (size_t)(hf*16 + r)*768 + sx*48 + q*4);
        }
        for (int i = tid; i < 4096; i += 256) {          // h: 16r * 16s * 16q
          int q = i & 15, sx = (i >> 4) & 15, r = i >> 8;
          *(float4*)(sm + r*S0 + 832 + sx*68 + q*4) =
              *(const float4*)(z0r + (size_t)(hf*16 + r)*1024 + sx*64 + q*4);
        }
        __syncthreads();
        #pragma unroll 1
        for (int bb = 0; bb < 16; ++bb) {
          const float4* xr = (const float4*)(sm + bb*S0 + ks*52);
          const float4* hr = (const float4*)(sm + bb*S0 + 832 + ks*68);
          float a0 = 0.f, a1 = 0.f, a2 = 0.f, a3 = 0.f;
          #pragma unroll
          for (int q = 0; q < 12; ++q) {
            float4 x4 = xr[q];
            a0 += wx0[q].x*x4.x; a1 += wx0[q].y*x4.y; a2 += wx0[q].z*x4.z; a3 += wx0[q].w*x4.w;
          }
          #pragma unroll
          for (int q = 0; q < 16; ++q) {
            float4 x4 = hr[q];
            a0 += wh0[q].x*x4.x; a1 += wh0[q].y*x4.y; a2 += wh0[q].z*x4.z; a3 += wh0[q].w*x4.w;
          }
          float v = (a0 + a1) + (a2 + a3);
          v += __shfl_xor(v, 1); v += __shfl_xor(v, 2); v += __shfl_xor(v, 4); v += __shfl_xor(v, 8);
          if (ks == 0) gb[jq*33 + hf*16 + bb] = bias0 + v;
        }
      }
      __syncthreads();
      if (tid < 128) {
        const int b2 = tid & 31, u_o = tid >> 5;
        float gi = gb[(0*4 + u_o)*33 + b2];
        float gf = gb[(1*4 + u_o)*33 + b2];
        float gg = gb[(2*4 + u_o)*33 + b2];
        float go = gb[(3*4 + u_o)*33 + b2];
        float c_new = sigm(gf)*c0r + sigm(gi)*tanhf(gg);
        float h = sigm(go)*tanhf(c_new);
        c0r = c_new;
        z0w[b2*1024 + gid*4 + u_o] = h;
        hb[u_o*32 + b2] = h;
      }
      __syncthreads();
      {
        const int b2 = tid & 31, aq = tid >> 5;
        float h0 = hb[0*32 + b2], h1 = hb[32 + b2], h2 = hb[64 + b2], h3 = hb[96 + b2];
        float* dp = dec_part + (gid & 7)*4096 + b2*128;
        #pragma unroll
        for (int ai = 0; ai < 16; ++ai) {
          int a = aq*16 + ai;
          float4 w = *(const float4*)(wdec_t + (size_t)a*1024 + gid*4);
          atomicAdd(dp + a, w.x*h0 + w.y*h1 + w.z*h2 + w.w*h3);
        }
      }
    }
    gbar(barcnt, 256u*(++nbar));

    // ======== P4: lstm1 (register weights) ========
    {
      const int S1 = 2176;  // 16*68 + 16*68
      #pragma unroll 1
      for (int hf = 0; hf < 2; ++hf) {
        __syncthreads();
        for (int i = tid; i < 4096; i += 256) {          // x = z0w
          int q = i & 15, sx = (i >> 4) & 15, r = i >> 8;
          *(float4*)(sm + r*S1 + sx*68 + q*4) =
              *(const float4*)(z0w + (size_t)(hf*16 + r)*1024 + sx*64 + q*4);
        }
        for (int i = tid; i < 4096; i += 256) {          // h = z1r
          int q = i & 15, sx = (i >> 4) & 15, r = i >> 8;
          *(float4*)(sm + r*S1 + 1088 + sx*68 + q*4) =
              *(const float4*)(z1r + (size_t)(hf*16 + r)*1024 + sx*64 + q*4);
        }
        __syncthreads();
        #pragma unroll 1
        for (int bb = 0; bb < 16; ++bb) {
          const float4* xr = (const float4*)(sm + bb*S1 + ks*68);
          const float4* hr = (const float4*)(sm + bb*S1 + 1088 + ks*68);
          float a0 = 0.f, a1 = 0.f, a2 = 0.f, a3 = 0.f;
          #pragma unroll
          for (int q = 0; q < 16; ++q) {
            float4 x4 = xr[q];
            a0 += wx1[q].x*x4.x; a1 += wx1[q].y*x4.y; a2 += wx1[q].z*x4.z; a3 += wx1[q].w*x4.w;
          }
          #pragma unroll
          for (int q = 0; q < 16; ++q) {
            float4 x4 = hr[q];
            a0 += wh1[q].x*x4.x; a1 += wh1[q].y*x4.y; a2 += wh1[q].z*x4.z; a3 += wh1[q].w*x4.w;
          }
          float v = (a0 + a1) + (a2 + a3);
          v += __shfl_xor(v, 1); v += __shfl_xor(v, 2); v += __shfl_xor(v, 4); v += __shfl_xor(v, 8);
          if (ks == 0) gb[jq*33 + hf*16 + bb] = bias1 + v;
        }
      }
      __syncthreads();
      if (tid < 128) {
        const int b2 = tid & 31, u_o = tid >> 5;
        float gi = gb[(0*4 + u_o)*33 + b2];
        float gf = gb[(1*4 + u_o)*33 + b2];
        float gg = gb[(2*4 + u_o)*33 + b2];
        float go = gb[(3*4 + u_o)*33 + b2];
        float c_new = sigm(gf)*c1r + sigm(gi)*tanhf(gg);
        float h = sigm(go)*tanhf(c_new);
        c1r = c_new;
        z1w[b2*1024 + gid*4 + u_o] = h;
      }
    }
    gbar(barcnt, 256u*(++nbar));
  }

  // ======== tail: outs/probs idx 255 from final z1 (parity 0) ========
  if (gid < 32) {
    const int b = gid;
    float* zs = sm;
    for (int i = tid; i < 1024; i += 256) zs[i] = z1buf[b*1024 + i];
    __syncthreads();
    if (tid < 80) {
      const float4* wp = (const float4*)(fw_t + tid*1024);
      const float4* zp = (const float4*)zs;
      float acc = feat_b[tid];
      for (int k4 = 0; k4 < 256; ++k4) {
        float4 w = wp[k4]; float4 z = zp[k4];
        acc += w.x*z.x + w.y*z.y + w.z*z.z + w.w*z.w;
      }
      outs_ws[(b*80 + tid)*256 + 255] = acc;
    } else if (tid == 80) {
      const float4* wp = (const float4*)prob_w;
      const float4* zp = (const float4*)zs;
      float acc = prob_b[0];
      for (int k4 = 0; k4 < 256; ++k4) {
        float4 w = wp[k4]; float4 z = zp[k4];
        acc += w.x*z.x + w.y*z.y + w.z*z.z + w.w*z.w;
      }
      probs_out[b*256 + 255] = acc;
    }
  }
}

// ---------------- postnet conv1d (k=5, pad=2), optional fused residual+transpose ----------------
__global__ void k_conv(const float* __restrict__ in, const float* __restrict__ wk,
                       int CI, int CO, float* __restrict__ out,
                       const float* __restrict__ resid, float* __restrict__ final_out) {
  int b = blockIdx.x, coT = blockIdx.y, lT = blockIdx.z;
  int l0 = lT*64;
  int tid = threadIdx.x;
  int lq = tid & 15, coq = tid >> 4;
  __shared__ float xs[16*68];
  __shared__ float wt[64*81];
  float acc[4][4];
  #pragma unroll
  for (int m = 0; m < 4; ++m)
    #pragma unroll
    for (int li = 0; li < 4; ++li) acc[m][li] = 0.f;
  int coBase = coT*64 + coq*4;
  for (int cc0 = 0; cc0 < CI; cc0 += 16) {
    __syncthreads();
    for (int i = tid; i < 16*68; i += 256) {
      int ci = i/68, pos = i - ci*68;
      int gl = l0 - 2 + pos;
      xs[i] = (gl >= 0 && gl < 256) ? in[((size_t)b*CI + cc0 + ci)*256 + gl] : 0.f;
    }
    for (int i = tid; i < 64*80; i += 256) {
      int co_i = i/80, rem = i - co_i*80;
      int cog = coT*64 + co_i;
      float w = (cog < CO) ? wk[(size_t)cog*CI*5 + (size_t)cc0*5 + rem] : 0.f;
      wt[co_i*81 + rem] = w;
    }
    __syncthreads();
    #pragma unroll 2
    for (int ci = 0; ci < 16; ++ci) {
      float4 xa = *(const float4*)&xs[ci*68 + lq*4];
      float4 xb = *(const float4*)&xs[ci*68 + lq*4 + 4];
      float x8[8] = {xa.x, xa.y, xa.z, xa.w, xb.x, xb.y, xb.z, xb.w};
      #pragma unroll
      for (int kk = 0; kk < 5; ++kk) {
        float w0 = wt[(coq*4+0)*81 + ci*5 + kk];
        float w1 = wt[(coq*4+1)*81 + ci*5 + kk];
        float w2 = wt[(coq*4+2)*81 + ci*5 + kk];
        float w3 = wt[(coq*4+3)*81 + ci*5 + kk];
        #pragma unroll
        for (int li = 0; li < 4; ++li) {
          float xv = x8[kk + li];
          acc[0][li] += w0*xv; acc[1][li] += w1*xv;
          acc[2][li] += w2*xv; acc[3][li] += w3*xv;
        }
      }
    }
  }
  if (final_out) {
    #pragma unroll
    for (int m = 0; m < 4; ++m) {
      int co = coBase + m;
      if (co < CO) {
        #pragma unroll
        for (int li = 0; li < 4; ++li) {
          int l = l0 + lq*4 + li;
          final_out[(size_t)(b*256 + l)*80 + co] =
              acc[m][li] + resid[((size_t)b*80 + co)*256 + l];
        }
      }
    }
  } else {
    #pragma unroll
    for (int m = 0; m < 4; ++m) {
      int co = coBase + m;
      if (co < CO) {
        float4 v = {acc[m][0], acc[m][1], acc[m][2], acc[m][3]};
        *(float4*)&out[((size_t)b*CO + co)*256 + l0 + lq*4] = v;
      }
    }
  }
}

// ---------------- BN train-mode stats ----------------
__global__ void k_bnstats(const float* __restrict__ x, const float* __restrict__ g,
                          const float* __restrict__ bt, float* __restrict__ scale,
                          float* __restrict__ shift) {
  int c = blockIdx.x;
  int tid = threadIdx.x;  // 256
  float s = 0.f, s2 = 0.f;
  for (int i = tid; i < 8192; i += 256) {
    int bb = i >> 8, l = i & 255;
    float v = x[((size_t)bb*512 + c)*256 + l];
    s += v; s2 += v*v;
  }
  __shared__ float rs[256], rs2[256];
  rs[tid] = s; rs2[tid] = s2;
  __syncthreads();
  for (int st = 128; st; st >>= 1) {
    if (tid < st) { rs[tid] += rs[tid + st]; rs2[tid] += rs2[tid + st]; }
    __syncthreads();
  }
  if (tid == 0) {
    float m = rs[0]/8192.f;
    float var = rs2[0]/8192.f - m*m;
    float inv = rsqrtf(var + 1e-5f);
    float sc = g[c]*inv;
    scale[c] = sc;
    shift[c] = bt[c] - m*sc;
  }
}

__global__ void k_bnapply(float* __restrict__ x, const float* __restrict__ scale,
                          const float* __restrict__ shift) {
  int i = blockIdx.x*256 + threadIdx.x;
  if (i < 32*512*256) {
    int c = (i >> 8) & 511;
    x[i] = tanhf(scale[c]*x[i] + shift[c]);
  }
}

// ---------------- launcher ----------------
extern "C" void kernel_launch(void* const* d_in, const int* in_sizes, int n_in,
                              void* d_out, int out_size, void* d_ws, size_t ws_size,
                              hipStream_t stream) {
  const float* hs       = (const float*)d_in[0];
  const int*   hlens    = (const int*)d_in[1];
  const int*   ylens    = (const int*)d_in[3];
  const float* w_enc    = (const float*)d_in[4];
  const float* b_enc    = (const float*)d_in[5];
  const float* w_dec    = (const float*)d_in[6];
  const float* loc_k    = (const float*)d_in[7];
  const float* w_loc    = (const float*)d_in[8];
  const float* gvec     = (const float*)d_in[9];
  const float* pre_w1   = (const float*)d_in[10];
  const float* pre_b1   = (const float*)d_in[11];
  const float* pre_w2   = (const float*)d_in[12];
  const float* pre_b2   = (const float*)d_in[13];
  const float* l0_wih   = (const float*)d_in[14];
  const float* l0_whh   = (const float*)d_in[15];
  const float* l0_b     = (const float*)d_in[16];
  const float* l1_wih   = (const float*)d_in[17];
  const float* l1_whh   = (const float*)d_in[18];
  const float* l1_b     = (const float*)d_in[19];
  const float* feat_w   = (const float*)d_in[20];
  const float* feat_b   = (const float*)d_in[21];
  const float* prob_w   = (const float*)d_in[22];
  const float* prob_b   = (const float*)d_in[23];
  const float* post_k1  = (const float*)d_in[24];
  const float* post_k2  = (const float*)d_in[25];
  const float* post_k3  = (const float*)d_in[26];
  const float* post_k4  = (const float*)d_in[27];
  const float* post_k5  = (const float*)d_in[28];
  const float* bn_g1 = (const float*)d_in[29]; const float* bn_b1 = (const float*)d_in[30];
  const float* bn_g2 = (const float*)d_in[31]; const float* bn_b2 = (const float*)d_in[32];
  const float* bn_g3 = (const float*)d_in[33]; const float* bn_b3 = (const float*)d_in[34];
  const float* bn_g4 = (const float*)d_in[35]; const float* bn_b4 = (const float*)d_in[36];

  float* ws = (float*)d_ws;
  float* enc_proj = ws + 0;
  float* aw       = ws + 2097152;
  float* e        = ws + 2113536;
  float* xc       = ws + 2134016;
  float* z0       = ws + 2158592;   // 2 x 32768
  float* z1       = ws + 2224128;   // 2 x 32768
  float* c0       = ws + 2289664;
  float* c1       = ws + 2322432;
  float* fw_t     = ws + 2355200;
  float* wdec_t   = ws + 2437120;
  float* outs_ws  = ws + 2568192;
  float* pn1      = ws + 3223552;
  float* pn2      = ws + 7417856;
  float* bsc      = ws + 11612160;
  float* bsh      = ws + 11612672;
  float* dec_part = pn2;                 // [8][32][128]
  unsigned* barcnt = (unsigned*)pn1;     // pn1 unused until postnet

  float* outp  = (float*)d_out;            // outs (B,L,80)
  float* probp = outp + 655360;            // probs (B,L)

  k_init<<<1154, 256, 0, stream>>>(z0, c0, z1, c1, aw, fw_t, wdec_t,
                                   feat_w, w_dec, hlens, ylens, outp, dec_part, barcnt);
  k_encproj<<<dim3(32, 32), 256, 0, stream>>>(hs, w_enc, b_enc, enc_proj);

  // the entire 256-step recurrence: one persistent kernel, weights register-resident
  k_loop<<<256, 256, 0, stream>>>(hs, hlens, enc_proj, loc_k, w_loc, gvec,
                                  pre_w1, pre_b1, pre_w2, pre_b2,
                                  l0_wih, l0_whh, l0_b, l1_wih, l1_whh, l1_b,
                                  fw_t, feat_b, prob_w, prob_b, wdec_t,
                                  aw, e, xc, z0, z1, outs_ws, probp, dec_part, barcnt);

  // postnet
  k_conv<<<dim3(32, 8, 4), 256, 0, stream>>>(outs_ws, post_k1, 80, 512, pn1, nullptr, nullptr);
  k_bnstats<<<512, 256, 0, stream>>>(pn1, bn_g1, bn_b1, bsc, bsh);
  k_bnapply<<<16384, 256, 0, stream>>>(pn1, bsc, bsh);

  k_conv<<<dim3(32, 8, 4), 256, 0, stream>>>(pn1, post_k2, 512, 512, pn2, nullptr, nullptr);
  k_bnstats<<<512, 256, 0, stream>>>(pn2, bn_g2, bn_b2, bsc, bsh);
  k_bnapply<<<16384, 256, 0, stream>>>(pn2, bsc, bsh);

  k_conv<<<dim3(32, 8, 4), 256, 0, stream>>>(pn2, post_k3, 512, 512, pn1, nullptr, nullptr);
  k_bnstats<<<512, 256, 0, stream>>>(pn1, bn_g3, bn_b3, bsc, bsh);
  k_bnapply<<<16384, 256, 0, stream>>>(pn1, bsc, bsh);

  k_conv<<<dim3(32, 8, 4), 256, 0, stream>>>(pn1, post_k4, 512, 512, pn2, nullptr, nullptr);
  k_bnstats<<<512, 256, 0, stream>>>(pn2, bn_g4, bn_b4, bsc, bsh);
  k_bnapply<<<16384, 256, 0, stream>>>(pn2, bsc, bsh);

  k_conv<<<dim3(32, 2, 4), 256, 0, stream>>>(pn2, post_k5, 512, 80, pn1, outs_ws, outp);
}

// Round 5
// 75008.734 us; speedup vs baseline: 1.2133x; 1.2133x over previous
//
#include <hip/hip_runtime.h>
#include <math.h>

// Problem constants
// B=32, T=512, IDIM=512, ODIM=80, L=256, DUNITS=1024, ATT=128, ACH=10, AK=31, PRE=256, POST=512

__device__ __forceinline__ float sigm(float x){ return 1.0f/(1.0f+__expf(-x)); }

// ---------------- workspace layout (floats) ----------------
// OFF_ENC  : 0         (2097152)  enc_proj (B,T,ATT)
// OFF_AW   : 2097152   (16384)    aw (B,T)
// OFF_E    : 2113536   (16384)    e  (B,T)
// OFF_XC   : 2134016   (24576)    xc (B,768)  [att_c | prenet]
// OFF_Z0   : 2158592   (65536)    z0 ping-pong (2,B,1024)
// OFF_Z1   : 2224128   (65536)    z1 ping-pong
// OFF_FWT  : 2355200   (81920)    feat_w transposed (80,1024)
// OFF_WDT  : 2437120   (131072)   w_dec transposed (128,1024)
// OFF_OUTS : 2568192   (655360)   outs_ws (B,80,L)
// OFF_PN1  : 3223552   (4194304)  postnet buf (word 0 = barrier counter during loop)
// OFF_PN2  : 7417856   (4194304)  [first 32768 = dec_part[8][32][128] during loop]
// OFF_BSC  : 11612160  (512)
// OFF_BSH  : 11612672  (512)

// ---------------- grid barrier (arrive + spin, device scope; proven R1/R4) ----------------
__device__ __forceinline__ void gbar(unsigned* cnt, unsigned target) {
  __syncthreads();
  if (threadIdx.x == 0) {
    __threadfence();
    __hip_atomic_fetch_add(cnt, 1u, __ATOMIC_RELAXED, __HIP_MEMORY_SCOPE_AGENT);
    while (__hip_atomic_load(cnt, __ATOMIC_RELAXED, __HIP_MEMORY_SCOPE_AGENT) < target)
      __builtin_amdgcn_s_sleep(2);
    __threadfence();
  }
  __syncthreads();
}

// ---------------- init ----------------
__global__ void k_init(float* __restrict__ z0, float* __restrict__ c0,
                       float* __restrict__ z1, float* __restrict__ c1,
                       float* __restrict__ aw, float* __restrict__ fw_t, float* __restrict__ wdec_t,
                       const float* __restrict__ feat_w, const float* __restrict__ w_dec,
                       const int* __restrict__ hlens, const int* __restrict__ ylens,
                       float* __restrict__ d_out, float* __restrict__ dec_part,
                       unsigned* __restrict__ barcnt) {
  int i = blockIdx.x*256 + threadIdx.x;
  if (i < 32768) {
    z0[i]=0.f; c0[i]=0.f; z1[i]=0.f; c1[i]=0.f;
  } else if (i < 49152) {
    int j = i - 32768; int b = j >> 9; int t = j & 511;
    int hl = hlens[b];
    aw[j] = (t < hl) ? 1.0f/(float)hl : 0.f;
  } else if (i < 131072) {
    int j = i - 49152; int od = j >> 10, k = j & 1023;
    fw_t[j] = feat_w[k*80 + od];
  } else if (i < 262144) {
    int j = i - 131072; int a = j >> 10, k = j & 1023;
    wdec_t[j] = w_dec[k*128 + a];
  } else if (i < 262176) {
    int b = i - 262144;
    d_out[663552 + b] = (float)ylens[b];
  } else if (i < 294944) {
    dec_part[i - 262176] = 0.f;     // dec partials for step 0 (z0 = 0)
  } else if (i == 294944) {
    *barcnt = 0u;
  }
}

// ---------------- enc_proj = hs @ w_enc + b_enc ----------------
__global__ void k_encproj(const float* __restrict__ hs, const float* __restrict__ w_enc,
                          const float* __restrict__ b_enc, float* __restrict__ enc_proj) {
  __shared__ float hsl[16*512];
  int b = blockIdx.x, t0 = blockIdx.y*16;
  int tid = threadIdx.x;  // 256
  for (int i = tid; i < 16*512; i += 256)
    hsl[i] = hs[(size_t)(b*512 + t0 + (i>>9))*512 + (i&511)];
  __syncthreads();
  int a = tid & 127, tq = tid >> 7;
  float acc[8];
  #pragma unroll
  for (int u=0;u<8;++u) acc[u]=0.f;
  for (int d=0; d<512; ++d) {
    float w = w_enc[d*128 + a];
    #pragma unroll
    for (int u=0;u<8;++u) acc[u] += hsl[(tq*8+u)*512 + d]*w;
  }
  float be = b_enc[a];
  #pragma unroll
  for (int u=0;u<8;++u)
    enc_proj[(size_t)(b*512 + t0 + tq*8 + u)*128 + a] = acc[u] + be;
}

// ---------------- attention energies, one (b, 64-t chunk) per block, 512 threads ----------------
__device__ __forceinline__ void att_e_512(
    int gid, int tid, float* __restrict__ sm,
    const float* __restrict__ aw, const float* __restrict__ loc_k,
    const float* __restrict__ w_loc, const float* __restrict__ gvec,
    const float* __restrict__ enc_proj, const float* __restrict__ dec_part,
    const int* __restrict__ hlens, float* __restrict__ e_out) {
  const int b = gid >> 3, t0 = (gid & 7)*64;
  const int hl = hlens[b];
  if (t0 >= hl) {                   // fully masked chunk: skip compute
    if (tid < 64) e_out[b*512 + t0 + tid] = -1e30f;
    return;
  }
  float* awin = sm;        // 94
  float* locl = sm + 96;   // 640
  float* redB = sm + 736;  // 128  (4 th x [lo16|hi16])
  if (tid < 94) {
    int idx = t0 - 15 + tid;
    awin[tid] = (idx >= 0 && idx < 512) ? aw[b*512 + idx] : 0.f;
  }
  __syncthreads();
  for (int i = tid; i < 640; i += 512) {
    int c = i >> 6, tt = i & 63;
    float sacc = 0.f;
    #pragma unroll
    for (int k = 0; k < 31; ++k) sacc += awin[tt + k]*loc_k[c*31 + k];
    locl[i] = sacc;
  }
  __syncthreads();
  const int a = tid & 127, th = tid >> 7;
  float dec_a = 0.f;
  #pragma unroll
  for (int sl = 0; sl < 8; ++sl) dec_a += dec_part[sl*4096 + b*128 + a];
  const float gv = gvec[a];
  float wl[10];
  #pragma unroll
  for (int c = 0; c < 10; ++c) wl[c] = w_loc[c*128 + a];
  #pragma unroll 2
  for (int tt = 0; tt < 16; ++tt) {
    const int tl = th*16 + tt;
    float sv = enc_proj[(size_t)(b*512 + t0 + tl)*128 + a] + dec_a;
    #pragma unroll
    for (int c = 0; c < 10; ++c) sv += locl[c*64 + tl]*wl[c];
    float v = tanhf(sv)*gv;
    #pragma unroll
    for (int off = 32; off; off >>= 1) v += __shfl_down(v, off);
    if ((tid & 63) == 0) redB[th*32 + ((tid >> 6) & 1)*16 + tt] = v;
  }
  __syncthreads();
  if (tid < 64) {
    const int t = t0 + tid;
    float ee = redB[(tid >> 4)*32 + (tid & 15)] + redB[(tid >> 4)*32 + 16 + (tid & 15)];
    e_out[b*512 + t] = (t < hl) ? ee : -1e30f;
  }
}

// ---------------- persistent decoder: LSTM weights register-resident (120 VGPR/thread) ----------------
// grid 256 x 512. thread = (jq = tid>>5 in [0,16), ks = tid&31 in [0,32)).
// Block gid owns j-rows {gate*1024 + gid*4 + uo}. Thread holds the ks-th 1/32
// k-slice of its row jq for all 4 weight matrices: 6+8+8+8 = 30 float4 = 120 VGPRs.
// 512 thr/block = 8 waves/CU = 2 waves/SIMD (VGPR cap 256, enforced by launch_bounds).
__global__ __launch_bounds__(512, 2) void k_loop(
    const float* __restrict__ hs, const int* __restrict__ hlens,
    const float* __restrict__ enc_proj, const float* __restrict__ loc_k,
    const float* __restrict__ w_loc, const float* __restrict__ gvec,
    const float* __restrict__ pre_w1, const float* __restrict__ pre_b1,
    const float* __restrict__ pre_w2, const float* __restrict__ pre_b2,
    const float* __restrict__ l0_wih, const float* __restrict__ l0_whh, const float* __restrict__ l0_b,
    const float* __restrict__ l1_wih, const float* __restrict__ l1_whh, const float* __restrict__ l1_b,
    const float* __restrict__ fw_t, const float* __restrict__ feat_b,
    const float* __restrict__ prob_w, const float* __restrict__ prob_b,
    const float* __restrict__ wdec_t,
    float* __restrict__ aw, float* __restrict__ e_buf, float* __restrict__ xc,
    float* __restrict__ z0buf, float* __restrict__ z1buf,
    float* __restrict__ outs_ws, float* __restrict__ probs_out,
    float* __restrict__ dec_part, unsigned* __restrict__ barcnt) {
  __shared__ float sm[19090];   // 76.4 KB
  const int gid = blockIdx.x;
  const int tid = threadIdx.x;
  const int jq = tid >> 5, ks = tid & 31;
  const int gate = jq >> 2, uo = jq & 3;
  const int jrow = gate*1024 + gid*4 + uo;
  float* gb = sm + 18432;   // 528
  float* hb = sm + 18960;   // 128
  float4* sm4a = (float4*)sm;            // x staging: 8 rows, stride 224 or 288 f4
  float4* sm4b = (float4*)(sm + 9216);   // h staging: 8 rows, stride 288 f4

  // ---- one-time weight preload: 30 float4 = 120 VGPRs ----
  float4 wx0[6], wh0[8], wx1[8], wh1[8];
  {
    const float4* p0 = (const float4*)(l0_wih + (size_t)jrow*768 + ks*24);
    #pragma unroll
    for (int q = 0; q < 6; ++q) wx0[q] = p0[q];
    const float4* p1 = (const float4*)(l0_whh + (size_t)jrow*1024 + ks*32);
    #pragma unroll
    for (int q = 0; q < 8; ++q) wh0[q] = p1[q];
    const float4* p2 = (const float4*)(l1_wih + (size_t)jrow*1024 + ks*32);
    #pragma unroll
    for (int q = 0; q < 8; ++q) wx1[q] = p2[q];
    const float4* p3 = (const float4*)(l1_whh + (size_t)jrow*1024 + ks*32);
    #pragma unroll
    for (int q = 0; q < 8; ++q) wh1[q] = p3[q];
  }
  const float bias0 = l0_b[jrow], bias1 = l1_b[jrow];
  float c0r = 0.f, c1r = 0.f;   // c-state: tid<128 owns (b=tid&31, u=gid*4+(tid>>5))
  unsigned nbar = 0;

  // ---- prologue: e(0) from aw0 and dec=0 ----
  att_e_512(gid, tid, sm, aw, loc_k, w_loc, gvec, enc_proj, dec_part, hlens, e_buf);
  gbar(barcnt, 256u*(++nbar));

  for (int s = 0; s < 256; ++s) {
    const int p = s & 1;
    const float* z0r = z0buf + p*32768; float* z0w = z0buf + (1-p)*32768;
    const float* z1r = z1buf + p*32768; float* z1w = z1buf + (1-p)*32768;

    // ======== PH_A: softmax + context (all blocks); feat/prob/prenet (blocks 0..31) ========
    {
      if (gid < 32 && tid < 128) {   // zero dec_part (consumed by att_e in PH_C(s-1))
        #pragma unroll
        for (int sl = 0; sl < 8; ++sl) dec_part[sl*4096 + gid*128 + tid] = 0.f;
      }
      const int b = gid >> 3, dc = gid & 7;
      const int hl = hlens[b];
      float* aws  = sm;         // 512
      float* red  = sm + 512;   // 16
      float* cred = sm + 528;   // 512
      const float ev = e_buf[b*512 + tid];
      float m = ev;
      #pragma unroll
      for (int off = 32; off; off >>= 1) m = fmaxf(m, __shfl_xor(m, off));
      if ((tid & 63) == 0) red[tid >> 6] = m;
      __syncthreads();
      m = fmaxf(fmaxf(fmaxf(red[0], red[1]), fmaxf(red[2], red[3])),
                fmaxf(fmaxf(red[4], red[5]), fmaxf(red[6], red[7])));
      const float pv = __expf(ev - m);
      float ssum = pv;
      #pragma unroll
      for (int off = 32; off; off >>= 1) ssum += __shfl_xor(ssum, off);
      if ((tid & 63) == 0) red[8 + (tid >> 6)] = ssum;
      __syncthreads();
      const float inv = 1.0f/(((red[8] + red[9]) + (red[10] + red[11])) +
                              ((red[12] + red[13]) + (red[14] + red[15])));
      const float av = pv*inv;
      aws[tid] = av;
      if (dc == 0) aw[b*512 + tid] = av;
      __syncthreads();
      const int d = dc*64 + (tid & 63), w = tid >> 6;
      const int base = w*64;
      int tcnt = hl - base; tcnt = tcnt < 0 ? 0 : (tcnt > 64 ? 64 : tcnt);
      const float* hp  = hs + (size_t)(b*512 + base)*512 + d;
      const float* awp = aws + base;
      float acc = 0.f;
      #pragma unroll 8
      for (int t = 0; t < tcnt; ++t) acc += awp[t]*hp[(size_t)t*512];
      cred[w*64 + (tid & 63)] = acc;
      __syncthreads();
      if (tid < 64) {
        float s8 = ((cred[tid] + cred[64 + tid]) + (cred[128 + tid] + cred[192 + tid])) +
                   ((cred[256 + tid] + cred[320 + tid]) + (cred[384 + tid] + cred[448 + tid]));
        xc[b*768 + dc*64 + tid] = s8;
      }
      if (gid < 32) {   // feat/prob/prenet for b = gid (block-uniform branch)
        const int bb = gid;
        float* zs   = sm + 1040;  // 1024
        float* prev = sm + 2064;  // 80
        float* h1s  = sm + 2144;  // 256
        __syncthreads();
        for (int i = tid; i < 1024; i += 512) zs[i] = z1r[bb*1024 + i];
        __syncthreads();
        if (tid < 80) {
          const float4* wp = (const float4*)(fw_t + tid*1024);
          const float4* zp = (const float4*)zs;
          float acc2 = feat_b[tid];
          for (int k4 = 0; k4 < 256; ++k4) {
            float4 w4 = wp[k4]; float4 z4 = zp[k4];
            acc2 += w4.x*z4.x + w4.y*z4.y + w4.z*z4.z + w4.w*z4.w;
          }
          prev[tid] = acc2;
          if (s > 0) outs_ws[(bb*80 + tid)*256 + (s-1)] = acc2;
        } else if (tid == 80) {
          const float4* wp = (const float4*)prob_w;
          const float4* zp = (const float4*)zs;
          float acc2 = prob_b[0];
          for (int k4 = 0; k4 < 256; ++k4) {
            float4 w4 = wp[k4]; float4 z4 = zp[k4];
            acc2 += w4.x*z4.x + w4.y*z4.y + w4.z*z4.z + w4.w*z4.w;
          }
          if (s > 0) probs_out[bb*256 + (s-1)] = acc2;
        }
        __syncthreads();
        if (tid < 256) {
          float acc2 = pre_b1[tid];
          for (int k = 0; k < 80; ++k) acc2 += prev[k]*pre_w1[k*256 + tid];
          h1s[tid] = fmaxf(acc2, 0.f);
        }
        __syncthreads();
        if (tid < 256) {
          float acc2 = pre_b2[tid];
          for (int k = 0; k < 256; ++k) acc2 += h1s[k]*pre_w2[k*256 + tid];
          xc[bb*768 + 512 + tid] = fmaxf(acc2, 0.f);
        }
      }
    }
    gbar(barcnt, 256u*(++nbar));

    // ======== PH_B: lstm0 (register weights) + dec_part atomics ========
    {
      const float4* xc4  = (const float4*)xc;
      const float4* z0r4 = (const float4*)z0r;
      #pragma unroll 1
      for (int c = 0; c < 4; ++c) {   // 8-b chunks
        __syncthreads();
        for (int i = tid; i < 1536; i += 512) {   // x rows (768): slice stride 7 f4
          int r = i/192, k4 = i - r*192;
          int sl = k4/6, wi = k4 - sl*6;
          sm4a[r*224 + sl*7 + wi] = xc4[(size_t)(c*8 + r)*192 + k4];
        }
        for (int i = tid; i < 2048; i += 512) {   // h rows (1024): slice stride 9 f4
          int r = i >> 8, k4 = i & 255;
          int sl = k4 >> 3, wi = k4 & 7;
          sm4b[r*288 + sl*9 + wi] = z0r4[(size_t)(c*8 + r)*256 + k4];
        }
        __syncthreads();
        #pragma unroll 1
        for (int bb = 0; bb < 8; ++bb) {
          const float4* xr = sm4a + bb*224 + ks*7;
          const float4* hr = sm4b + bb*288 + ks*9;
          float a0 = 0.f, a1 = 0.f, a2 = 0.f, a3 = 0.f;
          #pragma unroll
          for (int q = 0; q < 6; ++q) {
            float4 x4 = xr[q];
            a0 += wx0[q].x*x4.x; a1 += wx0[q].y*x4.y; a2 += wx0[q].z*x4.z; a3 += wx0[q].w*x4.w;
          }
          #pragma unroll
          for (int q = 0; q < 8; ++q) {
            float4 x4 = hr[q];
            a0 += wh0[q].x*x4.x; a1 += wh0[q].y*x4.y; a2 += wh0[q].z*x4.z; a3 += wh0[q].w*x4.w;
          }
          float v = (a0 + a1) + (a2 + a3);
          v += __shfl_xor(v, 1); v += __shfl_xor(v, 2); v += __shfl_xor(v, 4);
          v += __shfl_xor(v, 8); v += __shfl_xor(v, 16);
          if (ks == 0) gb[jq*33 + c*8 + bb] = bias0 + v;
        }
      }
      __syncthreads();
      if (tid < 128) {
        const int b2 = tid & 31, u_o = tid >> 5;
        float gi = gb[(0*4 + u_o)*33 + b2];
        float gf = gb[(1*4 + u_o)*33 + b2];
        float gg = gb[(2*4 + u_o)*33 + b2];
        float go = gb[(3*4 + u_o)*33 + b2];
        float c_new = sigm(gf)*c0r + sigm(gi)*tanhf(gg);
        float h = sigm(go)*tanhf(c_new);
        c0r = c_new;
        z0w[b2*1024 + gid*4 + u_o] = h;
        hb[u_o*32 + b2] = h;
      }
      __syncthreads();
      {
        const int b2 = tid & 31, aq = tid >> 5;   // 16 a-groups of 8
        float h0 = hb[b2], h1 = hb[32 + b2], h2 = hb[64 + b2], h3 = hb[96 + b2];
        float* dp = dec_part + (gid & 7)*4096 + b2*128;
        #pragma unroll
        for (int ai = 0; ai < 8; ++ai) {
          int a = aq*8 + ai;
          float4 w4 = *(const float4*)(wdec_t + (size_t)a*1024 + gid*4);
          atomicAdd(dp + a, w4.x*h0 + w4.y*h1 + w4.z*h2 + w4.w*h3);
        }
      }
    }
    gbar(barcnt, 256u*(++nbar));

    // ======== PH_C: lstm1 (register weights) + att_e for step s+1 ========
    {
      const float4* z0w4 = (const float4*)z0w;
      const float4* z1r4 = (const float4*)z1r;
      #pragma unroll 1
      for (int c = 0; c < 4; ++c) {
        __syncthreads();
        for (int i = tid; i < 2048; i += 512) {   // x = z0w
          int r = i >> 8, k4 = i & 255;
          int sl = k4 >> 3, wi = k4 & 7;
          sm4a[r*288 + sl*9 + wi] = z0w4[(size_t)(c*8 + r)*256 + k4];
        }
        for (int i = tid; i < 2048; i += 512) {   // h = z1r
          int r = i >> 8, k4 = i & 255;
          int sl = k4 >> 3, wi = k4 & 7;
          sm4b[r*288 + sl*9 + wi] = z1r4[(size_t)(c*8 + r)*256 + k4];
        }
        __syncthreads();
        #pragma unroll 1
        for (int bb = 0; bb < 8; ++bb) {
          const float4* xr = sm4a + bb*288 + ks*9;
          const float4* hr = sm4b + bb*288 + ks*9;
          float a0 = 0.f, a1 = 0.f, a2 = 0.f, a3 = 0.f;
          #pragma unroll
          for (int q = 0; q < 8; ++q) {
            float4 x4 = xr[q];
            a0 += wx1[q].x*x4.x; a1 += wx1[q].y*x4.y; a2 += wx1[q].z*x4.z; a3 += wx1[q].w*x4.w;
          }
          #pragma unroll
          for (int q = 0; q < 8; ++q) {
            float4 x4 = hr[q];
            a0 += wh1[q].x*x4.x; a1 += wh1[q].y*x4.y; a2 += wh1[q].z*x4.z; a3 += wh1[q].w*x4.w;
          }
          float v = (a0 + a1) + (a2 + a3);
          v += __shfl_xor(v, 1); v += __shfl_xor(v, 2); v += __shfl_xor(v, 4);
          v += __shfl_xor(v, 8); v += __shfl_xor(v, 16);
          if (ks == 0) gb[jq*33 + c*8 + bb] = bias1 + v;
        }
      }
      __syncthreads();
      if (tid < 128) {
        const int b2 = tid & 31, u_o = tid >> 5;
        float gi = gb[(0*4 + u_o)*33 + b2];
        float gf = gb[(1*4 + u_o)*33 + b2];
        float gg = gb[(2*4 + u_o)*33 + b2];
        float go = gb[(3*4 + u_o)*33 + b2];
        float c_new = sigm(gf)*c1r + sigm(gi)*tanhf(gg);
        float h = sigm(go)*tanhf(c_new);
        c1r = c_new;
        z1w[b2*1024 + gid*4 + u_o] = h;
      }
      __syncthreads();
      // att_e for step s+1 (uses aw(s) from PH_A, dec_part from PH_B)
      att_e_512(gid, tid, sm, aw, loc_k, w_loc, gvec, enc_proj, dec_part, hlens, e_buf);
    }
    gbar(barcnt, 256u*(++nbar));
  }

  // ======== tail: outs/probs idx 255 from final z1 (parity 0) ========
  if (gid < 32) {
    float* zs = sm;
    for (int i = tid; i < 1024; i += 512) zs[i] = z1buf[gid*1024 + i];
    __syncthreads();
    if (tid < 80) {
      const float4* wp = (const float4*)(fw_t + tid*1024);
      const float4* zp = (const float4*)zs;
      float acc = feat_b[tid];
      for (int k4 = 0; k4 < 256; ++k4) {
        float4 w4 = wp[k4]; float4 z4 = zp[k4];
        acc += w4.x*z4.x + w4.y*z4.y + w4.z*z4.z + w4.w*z4.w;
      }
      outs_ws[(gid*80 + tid)*256 + 255] = acc;
    } else if (tid == 80) {
      const float4* wp = (const float4*)prob_w;
      const float4* zp = (const float4*)zs;
      float acc = prob_b[0];
      for (int k4 = 0; k4 < 256; ++k4) {
        float4 w4 = wp[k4]; float4 z4 = zp[k4];
        acc += w4.x*z4.x + w4.y*z4.y + w4.z*z4.z + w4.w*z4.w;
      }
      probs_out[gid*256 + 255] = acc;
    }
  }
}

// ---------------- postnet conv1d (k=5, pad=2), optional fused residual+transpose ----------------
__global__ void k_conv(const float* __restrict__ in, const float* __restrict__ wk,
                       int CI, int CO, float* __restrict__ out,
                       const float* __restrict__ resid, float* __restrict__ final_out) {
  int b = blockIdx.x, coT = blockIdx.y, lT = blockIdx.z;
  int l0 = lT*64;
  int tid = threadIdx.x;
  int lq = tid & 15, coq = tid >> 4;
  __shared__ float xs[16*68];
  __shared__ float wt[64*81];
  float acc[4][4];
  #pragma unroll
  for (int m = 0; m < 4; ++m)
    #pragma unroll
    for (int li = 0; li < 4; ++li) acc[m][li] = 0.f;
  int coBase = coT*64 + coq*4;
  for (int cc0 = 0; cc0 < CI; cc0 += 16) {
    __syncthreads();
    for (int i = tid; i < 16*68; i += 256) {
      int ci = i/68, pos = i - ci*68;
      int gl = l0 - 2 + pos;
      xs[i] = (gl >= 0 && gl < 256) ? in[((size_t)b*CI + cc0 + ci)*256 + gl] : 0.f;
    }
    for (int i = tid; i < 64*80; i += 256) {
      int co_i = i/80, rem = i - co_i*80;
      int cog = coT*64 + co_i;
      float w = (cog < CO) ? wk[(size_t)cog*CI*5 + (size_t)cc0*5 + rem] : 0.f;
      wt[co_i*81 + rem] = w;
    }
    __syncthreads();
    #pragma unroll 2
    for (int ci = 0; ci < 16; ++ci) {
      float4 xa = *(const float4*)&xs[ci*68 + lq*4];
      float4 xb = *(const float4*)&xs[ci*68 + lq*4 + 4];
      float x8[8] = {xa.x, xa.y, xa.z, xa.w, xb.x, xb.y, xb.z, xb.w};
      #pragma unroll
      for (int kk = 0; kk < 5; ++kk) {
        float w0 = wt[(coq*4+0)*81 + ci*5 + kk];
        float w1 = wt[(coq*4+1)*81 + ci*5 + kk];
        float w2 = wt[(coq*4+2)*81 + ci*5 + kk];
        float w3 = wt[(coq*4+3)*81 + ci*5 + kk];
        #pragma unroll
        for (int li = 0; li < 4; ++li) {
          float xv = x8[kk + li];
          acc[0][li] += w0*xv; acc[1][li] += w1*xv;
          acc[2][li] += w2*xv; acc[3][li] += w3*xv;
        }
      }
    }
  }
  if (final_out) {
    #pragma unroll
    for (int m = 0; m < 4; ++m) {
      int co = coBase + m;
      if (co < CO) {
        #pragma unroll
        for (int li = 0; li < 4; ++li) {
          int l = l0 + lq*4 + li;
          final_out[(size_t)(b*256 + l)*80 + co] =
              acc[m][li] + resid[((size_t)b*80 + co)*256 + l];
        }
      }
    }
  } else {
    #pragma unroll
    for (int m = 0; m < 4; ++m) {
      int co = coBase + m;
      if (co < CO) {
        float4 v = {acc[m][0], acc[m][1], acc[m][2], acc[m][3]};
        *(float4*)&out[((size_t)b*CO + co)*256 + l0 + lq*4] = v;
      }
    }
  }
}

// ---------------- BN train-mode stats ----------------
__global__ void k_bnstats(const float* __restrict__ x, const float* __restrict__ g,
                          const float* __restrict__ bt, float* __restrict__ scale,
                          float* __restrict__ shift) {
  int c = blockIdx.x;
  int tid = threadIdx.x;  // 256
  float s = 0.f, s2 = 0.f;
  for (int i = tid; i < 8192; i += 256) {
    int bb = i >> 8, l = i & 255;
    float v = x[((size_t)bb*512 + c)*256 + l];
    s += v; s2 += v*v;
  }
  __shared__ float rs[256], rs2[256];
  rs[tid] = s; rs2[tid] = s2;
  __syncthreads();
  for (int st = 128; st; st >>= 1) {
    if (tid < st) { rs[tid] += rs[tid + st]; rs2[tid] += rs2[tid + st]; }
    __syncthreads();
  }
  if (tid == 0) {
    float m = rs[0]/8192.f;
    float var = rs2[0]/8192.f - m*m;
    float inv = rsqrtf(var + 1e-5f);
    float sc = g[c]*inv;
    scale[c] = sc;
    shift[c] = bt[c] - m*sc;
  }
}

__global__ void k_bnapply(float* __restrict__ x, const float* __restrict__ scale,
                          const float* __restrict__ shift) {
  int i = blockIdx.x*256 + threadIdx.x;
  if (i < 32*512*256) {
    int c = (i >> 8) & 511;
    x[i] = tanhf(scale[c]*x[i] + shift[c]);
  }
}

// ---------------- launcher ----------------
extern "C" void kernel_launch(void* const* d_in, const int* in_sizes, int n_in,
                              void* d_out, int out_size, void* d_ws, size_t ws_size,
                              hipStream_t stream) {
  const float* hs       = (const float*)d_in[0];
  const int*   hlens    = (const int*)d_in[1];
  const int*   ylens    = (const int*)d_in[3];
  const float* w_enc    = (const float*)d_in[4];
  const float* b_enc    = (const float*)d_in[5];
  const float* w_dec    = (const float*)d_in[6];
  const float* loc_k    = (const float*)d_in[7];
  const float* w_loc    = (const float*)d_in[8];
  const float* gvec     = (const float*)d_in[9];
  const float* pre_w1   = (const float*)d_in[10];
  const float* pre_b1   = (const float*)d_in[11];
  const float* pre_w2   = (const float*)d_in[12];
  const float* pre_b2   = (const float*)d_in[13];
  const float* l0_wih   = (const float*)d_in[14];
  const float* l0_whh   = (const float*)d_in[15];
  const float* l0_b     = (const float*)d_in[16];
  const float* l1_wih   = (const float*)d_in[17];
  const float* l1_whh   = (const float*)d_in[18];
  const float* l1_b     = (const float*)d_in[19];
  const float* feat_w   = (const float*)d_in[20];
  const float* feat_b   = (const float*)d_in[21];
  const float* prob_w   = (const float*)d_in[22];
  const float* prob_b   = (const float*)d_in[23];
  const float* post_k1  = (const float*)d_in[24];
  const float* post_k2  = (const float*)d_in[25];
  const float* post_k3  = (const float*)d_in[26];
  const float* post_k4  = (const float*)d_in[27];
  const float* post_k5  = (const float*)d_in[28];
  const float* bn_g1 = (const float*)d_in[29]; const float* bn_b1 = (const float*)d_in[30];
  const float* bn_g2 = (const float*)d_in[31]; const float* bn_b2 = (const float*)d_in[32];
  const float* bn_g3 = (const float*)d_in[33]; const float* bn_b3 = (const float*)d_in[34];
  const float* bn_g4 = (const float*)d_in[35]; const float* bn_b4 = (const float*)d_in[36];

  float* ws = (float*)d_ws;
  float* enc_proj = ws + 0;
  float* aw       = ws + 2097152;
  float* e        = ws + 2113536;
  float* xc       = ws + 2134016;
  float* z0       = ws + 2158592;   // 2 x 32768
  float* z1       = ws + 2224128;   // 2 x 32768
  float* c0       = ws + 2289664;
  float* c1       = ws + 2322432;
  float* fw_t     = ws + 2355200;
  float* wdec_t   = ws + 2437120;
  float* outs_ws  = ws + 2568192;
  float* pn1      = ws + 3223552;
  float* pn2      = ws + 7417856;
  float* bsc      = ws + 11612160;
  float* bsh      = ws + 11612672;
  float* dec_part = pn2;                 // [8][32][128]
  unsigned* barcnt = (unsigned*)pn1;     // pn1 unused until postnet

  float* outp  = (float*)d_out;            // outs (B,L,80)
  float* probp = outp + 655360;            // probs (B,L)

  k_init<<<1154, 256, 0, stream>>>(z0, c0, z1, c1, aw, fw_t, wdec_t,
                                   feat_w, w_dec, hlens, ylens, outp, dec_part, barcnt);
  k_encproj<<<dim3(32, 32), 256, 0, stream>>>(hs, w_enc, b_enc, enc_proj);

  // the entire 256-step recurrence: one persistent kernel, weights register-resident
  k_loop<<<256, 512, 0, stream>>>(hs, hlens, enc_proj, loc_k, w_loc, gvec,
                                  pre_w1, pre_b1, pre_w2, pre_b2,
                                  l0_wih, l0_whh, l0_b, l1_wih, l1_whh, l1_b,
                                  fw_t, feat_b, prob_w, prob_b, wdec_t,
                                  aw, e, xc, z0, z1, outs_ws, probp, dec_part, barcnt);

  // postnet
  k_conv<<<dim3(32, 8, 4), 256, 0, stream>>>(outs_ws, post_k1, 80, 512, pn1, nullptr, nullptr);
  k_bnstats<<<512, 256, 0, stream>>>(pn1, bn_g1, bn_b1, bsc, bsh);
  k_bnapply<<<16384, 256, 0, stream>>>(pn1, bsc, bsh);

  k_conv<<<dim3(32, 8, 4), 256, 0, stream>>>(pn1, post_k2, 512, 512, pn2, nullptr, nullptr);
  k_bnstats<<<512, 256, 0, stream>>>(pn2, bn_g2, bn_b2, bsc, bsh);
  k_bnapply<<<16384, 256, 0, stream>>>(pn2, bsc, bsh);

  k_conv<<<dim3(32, 8, 4), 256, 0, stream>>>(pn2, post_k3, 512, 512, pn1, nullptr, nullptr);
  k_bnstats<<<512, 256, 0, stream>>>(pn1, bn_g3, bn_b3, bsc, bsh);
  k_bnapply<<<16384, 256, 0, stream>>>(pn1, bsc, bsh);

  k_conv<<<dim3(32, 8, 4), 256, 0, stream>>>(pn1, post_k4, 512, 512, pn2, nullptr, nullptr);
  k_bnstats<<<512, 256, 0, stream>>>(pn2, bn_g4, bn_b4, bsc, bsh);
  k_bnapply<<<16384, 256, 0, stream>>>(pn2, bsc, bsh);

  k_conv<<<dim3(32, 2, 4), 256, 0, stream>>>(pn2, post_k5, 512, 80, pn1, outs_ws, outp);
}